// Round 4
// baseline (273.591 us; speedup 1.0000x reference)
//
#include <hip/hip_runtime.h>
#include <hip/hip_bf16.h>
#include <math.h>

#define N_NODES 16384
#define N_EDGES 524288
#define F_IN 128
#define H1 256
#define H2 256
#define D1 64
#define NEWADJ_BLOCKS 512

typedef __attribute__((ext_vector_type(8))) short short8;
typedef __attribute__((ext_vector_type(4))) float floatx4;
typedef unsigned short ushort_t;
typedef unsigned int uint_t;

__device__ inline float bf2f(ushort_t u) {
    union { uint_t i; float f; } v;
    v.i = ((uint_t)u) << 16;
    return v.f;
}
__device__ inline ushort_t f2bs(float x) {
    __hip_bfloat16 h = __float2bfloat16(x);   // RNE
    return *reinterpret_cast<ushort_t*>(&h);
}

// ---------------- CSR build ----------------

__global__ void hist_kernel(const int* __restrict__ dst, int* __restrict__ indeg) {
    int e = blockIdx.x * 256 + threadIdx.x;
    if (e < N_EDGES) atomicAdd(&indeg[dst[e]], 1);
}

__global__ void scan_kernel(const int* __restrict__ indeg, int* __restrict__ rowptr,
                            int* __restrict__ cursor, float* __restrict__ dinv) {
    __shared__ int part[256];
    int t = threadIdx.x;
    int base = t * 64;
    int s = 0;
    for (int i = 0; i < 64; ++i) s += indeg[base + i];
    part[t] = s;
    __syncthreads();
    for (int off = 1; off < 256; off <<= 1) {
        int v = part[t];
        int add = (t >= off) ? part[t - off] : 0;
        __syncthreads();
        part[t] = v + add;
        __syncthreads();
    }
    int run = (t == 0) ? 0 : part[t - 1];
    for (int i = 0; i < 64; ++i) {
        int d = indeg[base + i];
        rowptr[base + i] = run;
        cursor[base + i] = run;
        dinv[base + i] = rsqrtf((float)(d + 1));   // +1 self loop
        run += d;
    }
    if (t == 255) rowptr[N_NODES] = run;
}

__global__ void fill_kernel(const int* __restrict__ src, const int* __restrict__ dst,
                            int* __restrict__ cursor, int* __restrict__ col) {
    int e = blockIdx.x * 256 + threadIdx.x;
    if (e < N_EDGES) {
        int d = dst[e];
        int p = atomicAdd(&cursor[d], 1);
        col[p] = src[e];
    }
}

// ---------------- prep: converts + transposes ----------------
// blocks [0,2048): z[n][k] = bf16(features[n][k] * dinv[n])   (Agg-first prescale)
// blocks [2048,2176): W1t[n][k] = W1[k][n]   (256x128)
// blocks [2176,2432): W2t[n][k] = W2[k][n]   (256x256)
// blocks [2432,2496): fc1bf = convert(fc1_w) (64x256, already [out][k])
__global__ __launch_bounds__(256) void prep_kernel(
    const float* __restrict__ features, const float* __restrict__ W1,
    const float* __restrict__ W2, const float* __restrict__ fc1_w,
    const float* __restrict__ dinv,
    ushort_t* __restrict__ z, ushort_t* __restrict__ W1t,
    ushort_t* __restrict__ W2t, ushort_t* __restrict__ fc1bf) {
    int b = blockIdx.x, t = threadIdx.x;
    if (b < 2048) {
        int idx = (b * 256 + t) * 4;
        float di = dinv[idx >> 7];           // 4 consecutive elems same node
        float4 v = *(const float4*)&features[idx];
        uint_t lo = (uint_t)f2bs(v.x * di) | ((uint_t)f2bs(v.y * di) << 16);
        uint_t hi = (uint_t)f2bs(v.z * di) | ((uint_t)f2bs(v.w * di) << 16);
        uint2 p; p.x = lo; p.y = hi;
        *(uint2*)&z[idx] = p;
    } else if (b < 2176) {
        int idx = (b - 2048) * 256 + t;      // 0..32767
        int n = idx >> 7, k = idx & 127;
        W1t[idx] = f2bs(W1[k * 256 + n]);
    } else if (b < 2432) {
        int idx = (b - 2176) * 256 + t;      // 0..65535
        int n = idx >> 8, k = idx & 255;
        W2t[idx] = f2bs(W2[k * 256 + n]);
    } else {
        int idx = (b - 2432) * 256 + t;      // 0..16383
        fc1bf[idx] = f2bs(fc1_w[idx]);
    }
}

// ---------------- bf16 MFMA GEMM with fused epilogue ----------------
// A row-major [M][K] bf16, Bt [N][K] bf16; epilogue:
//   v = acc * (ROWSCALE?dinv[i]:1) + (BIAS?bias[j]:0); RELU optional
template <int BM, int BN, bool OUT_BF16, bool ROWSCALE, bool BIASF, bool RELU>
__global__ __launch_bounds__(256) void gemm_bf16(
    const ushort_t* __restrict__ A, const ushort_t* __restrict__ Bt,
    const float* __restrict__ rowscale, const float* __restrict__ bias,
    void* __restrict__ Cv, int K, int N) {
    constexpr int BK = 32;
    constexpr int LDA = BK + 8;              // pad: 2-way max (free, m136)
    constexpr int RM = BM / 2 / 16;
    constexpr int RN = BN / 2 / 16;
    __shared__ ushort_t As[BM * LDA];
    __shared__ ushort_t Bs[BN * LDA];
    const int tid = threadIdx.x;
    const int lane = tid & 63;
    const int wave = tid >> 6;
    const int m = lane & 15;
    const int quad = lane >> 4;
    const int row0 = blockIdx.y * BM;
    const int col0 = blockIdx.x * BN;
    const int wrow0 = (wave >> 1) * (BM / 2);
    const int wcol0 = (wave & 1) * (BN / 2);

    floatx4 acc[RM][RN];
    const floatx4 zero4 = {0.f, 0.f, 0.f, 0.f};
    #pragma unroll
    for (int i = 0; i < RM; ++i)
        #pragma unroll
        for (int j = 0; j < RN; ++j) acc[i][j] = zero4;

    for (int k0 = 0; k0 < K; k0 += BK) {
        __syncthreads();
        #pragma unroll
        for (int i = tid; i < BM * BK / 8; i += 256) {
            int e = i * 8;
            int r = e / BK, c = e % BK;
            *(uint4*)&As[r * LDA + c] =
                *(const uint4*)&A[(size_t)(row0 + r) * K + k0 + c];
        }
        #pragma unroll
        for (int i = tid; i < BN * BK / 8; i += 256) {
            int e = i * 8;
            int r = e / BK, c = e % BK;
            *(uint4*)&Bs[r * LDA + c] =
                *(const uint4*)&Bt[(size_t)(col0 + r) * K + k0 + c];
        }
        __syncthreads();
        short8 a[RM], b[RN];
        #pragma unroll
        for (int i = 0; i < RM; ++i)
            a[i] = *(const short8*)&As[(wrow0 + i * 16 + m) * LDA + quad * 8];
        #pragma unroll
        for (int j = 0; j < RN; ++j)
            b[j] = *(const short8*)&Bs[(wcol0 + j * 16 + m) * LDA + quad * 8];
        #pragma unroll
        for (int i = 0; i < RM; ++i)
            #pragma unroll
            for (int j = 0; j < RN; ++j)
                acc[i][j] = __builtin_amdgcn_mfma_f32_16x16x32_bf16(
                    a[i], b[j], acc[i][j], 0, 0, 0);
    }

    ushort_t* Cb = (ushort_t*)Cv;
    float* Cf = (float*)Cv;
    #pragma unroll
    for (int i = 0; i < RM; ++i) {
        int rbase = row0 + wrow0 + i * 16 + quad * 4;
        float rs4[4];
        #pragma unroll
        for (int r = 0; r < 4; ++r)
            rs4[r] = ROWSCALE ? rowscale[rbase + r] : 1.0f;
        #pragma unroll
        for (int j = 0; j < RN; ++j) {
            int cg = col0 + wcol0 + j * 16 + m;
            float bv = BIASF ? bias[cg] : 0.0f;
            #pragma unroll
            for (int r = 0; r < 4; ++r) {
                float v = acc[i][j][r] * rs4[r] + bv;
                if (RELU) v = fmaxf(v, 0.0f);
                if (OUT_BF16) Cb[(size_t)(rbase + r) * N + cg] = f2bs(v);
                else          Cf[(size_t)(rbase + r) * N + cg] = v;
            }
        }
    }
}

// ---------------- wave-per-node aggregation (no barriers) ----------------
// out[d][f] = bf16( dinv[d]*(y[d][f] + sum_nbr y[s][f]) + (BIASF?bias[f]:0) )
// V uints per lane: V=1 -> 128 features, V=2 -> 256 features.
template <int V, bool BIASF>
__global__ __launch_bounds__(256) void aggregate_wave(
    const ushort_t* __restrict__ y, const int* __restrict__ rowptr,
    const int* __restrict__ col, const float* __restrict__ dinv,
    const float* __restrict__ bias, ushort_t* __restrict__ out) {
    const int node = (blockIdx.x * 256 + threadIdx.x) >> 6;
    const int lane = threadIdx.x & 63;
    const int F = 128 * V;
    const int foff = lane * 2 * V;
    float acc[2 * V];
    {
        const uint_t* p = (const uint_t*)&y[(size_t)node * F + foff];
        #pragma unroll
        for (int v = 0; v < V; ++v) {
            uint_t u = p[v];
            acc[2 * v]     = bf2f((ushort_t)(u & 0xffff));
            acc[2 * v + 1] = bf2f((ushort_t)(u >> 16));
        }
    }
    const int s1 = rowptr[node + 1];
    for (int base = rowptr[node]; base < s1; base += 64) {
        int cnt = min(64, s1 - base);
        int myidx = (lane < cnt) ? col[base + lane] : 0;
        for (int i = 0; i < cnt; ++i) {
            int j = __shfl(myidx, i);
            const uint_t* p = (const uint_t*)&y[(size_t)j * F + foff];
            #pragma unroll
            for (int v = 0; v < V; ++v) {
                uint_t u = p[v];
                acc[2 * v]     += bf2f((ushort_t)(u & 0xffff));
                acc[2 * v + 1] += bf2f((ushort_t)(u >> 16));
            }
        }
    }
    float di = dinv[node];
    uint_t* po = (uint_t*)&out[(size_t)node * F + foff];
    #pragma unroll
    for (int v = 0; v < V; ++v) {
        float v0 = acc[2 * v] * di;
        float v1 = acc[2 * v + 1] * di;
        if (BIASF) { v0 += bias[foff + 2 * v]; v1 += bias[foff + 2 * v + 1]; }
        po[v] = (uint_t)f2bs(v0) | ((uint_t)f2bs(v1) << 16);
    }
}

// ---------------- assignment MLP tail (wave per node) ----------------
__global__ __launch_bounds__(256) void assign_kernel(
    const float* __restrict__ a1pre, const float* __restrict__ fc1_b,
    const float* __restrict__ fc2_w, const float* __restrict__ fc2_b,
    float* __restrict__ assign) {
    int n = blockIdx.x * 4 + (threadIdx.x >> 6);
    int t = threadIdx.x & 63;
    float a = tanhf(a1pre[(size_t)n * 64 + t] + fc1_b[t]);
    float p0 = a * fc2_w[t];
    float p1 = a * fc2_w[64 + t];
    #pragma unroll
    for (int off = 32; off; off >>= 1) {
        p0 += __shfl_down(p0, off);
        p1 += __shfl_down(p1, off);
    }
    if (t == 0) {
        p0 += fc2_b[0];
        p1 += fc2_b[1];
        float mx = fmaxf(p0, p1);
        float e0 = expf(p0 - mx), e1 = expf(p1 - mx);
        float inv = 1.0f / (e0 + e1);
        assign[n * 2 + 0] = e0 * inv;
        assign[n * 2 + 1] = e1 * inv;
    }
}

// ---------------- fused pooled reductions ----------------
// blocks [0,64): gf[k][f] = sum_n assign[n][k]*h2[n][f]
// blocks [64,64+NEWADJ_BLOCKS): new_adj partials
__global__ __launch_bounds__(256) void pool_kernel(
    const ushort_t* __restrict__ h2, const float* __restrict__ assign,
    const int* __restrict__ src, const int* __restrict__ dst,
    float* __restrict__ gf, float* __restrict__ part) {
    if (blockIdx.x < 64) {
        __shared__ float as0[256], as1[256];
        int f = threadIdx.x;
        int n0 = blockIdx.x * 256;
        as0[f] = assign[(n0 + f) * 2 + 0];
        as1[f] = assign[(n0 + f) * 2 + 1];
        __syncthreads();
        float acc0 = 0.f, acc1 = 0.f;
        for (int i = 0; i < 256; ++i) {
            float h = bf2f(h2[(size_t)(n0 + i) * 256 + f]);
            acc0 += as0[i] * h;
            acc1 += as1[i] * h;
        }
        atomicAdd(&gf[f], acc0);
        atomicAdd(&gf[256 + f], acc1);
    } else {
        __shared__ float red[4][4];
        int blk = blockIdx.x - 64;
        float a00 = 0.f, a01 = 0.f, a10 = 0.f, a11 = 0.f;
        for (int e = blk * 256 + threadIdx.x; e < N_EDGES;
             e += NEWADJ_BLOCKS * 256) {
            int s = src[e], d = dst[e];
            float s0 = assign[s * 2], s1 = assign[s * 2 + 1];
            float d0 = assign[d * 2], d1 = assign[d * 2 + 1];
            a00 += s0 * d0; a01 += s0 * d1; a10 += s1 * d0; a11 += s1 * d1;
        }
        #pragma unroll
        for (int off = 32; off; off >>= 1) {
            a00 += __shfl_down(a00, off);
            a01 += __shfl_down(a01, off);
            a10 += __shfl_down(a10, off);
            a11 += __shfl_down(a11, off);
        }
        int wave = threadIdx.x >> 6;
        if ((threadIdx.x & 63) == 0) {
            red[wave][0] = a00; red[wave][1] = a01;
            red[wave][2] = a10; red[wave][3] = a11;
        }
        __syncthreads();
        if (threadIdx.x < 4) {
            float v = red[0][threadIdx.x] + red[1][threadIdx.x] +
                      red[2][threadIdx.x] + red[3][threadIdx.x];
            part[blk * 4 + threadIdx.x] = v;
        }
    }
}

__global__ __launch_bounds__(256) void finalize_kernel(
    const float* __restrict__ gf, const float* __restrict__ part,
    float* __restrict__ out) {
    __shared__ float na[4];
    int t = threadIdx.x;
    int wave = t >> 6, lane = t & 63;
    float acc = 0.f;
    for (int i = lane; i < NEWADJ_BLOCKS; i += 64) acc += part[i * 4 + wave];
    #pragma unroll
    for (int off = 32; off; off >>= 1) acc += __shfl_down(acc, off);
    if (lane == 0) na[wave] = acc;
    __syncthreads();
    float g0 = gf[t], g1 = gf[256 + t];
    out[t] = 0.5f * (g0 + g1);
    out[256 + t] = fminf(fmaxf(g0, -100.f), 100.f);
    out[512 + t] = fminf(fmaxf(g1, -100.f), 100.f);
    if (t == 0) {
        float n00 = na[0], n01 = na[1], n10 = na[2], n11 = na[3];
        float den0 = fmaxf(fabsf(n00) + fabsf(n01), 1e-12f);
        float den1 = fmaxf(fabsf(n10) + fabsf(n11), 1e-12f);
        float x0 = n00 / den0 - 1.0f;
        float x1 = n11 / den1 - 1.0f;
        out[768] = 0.5f * (x0 * x0 + x1 * x1);
    }
}

// ---------------- launch ----------------

extern "C" void kernel_launch(void* const* d_in, const int* in_sizes, int n_in,
                              void* d_out, int out_size, void* d_ws, size_t ws_size,
                              hipStream_t stream) {
    const float* features = (const float*)d_in[0];
    const int* edges = (const int*)d_in[1];
    const int* src = edges;
    const int* dst = edges + N_EDGES;
    const float* W1 = (const float*)d_in[2];
    const float* b1 = (const float*)d_in[3];
    const float* W2 = (const float*)d_in[4];
    const float* b2 = (const float*)d_in[5];
    const float* fc1_w = (const float*)d_in[6];
    const float* fc1_b = (const float*)d_in[7];
    const float* fc2_w = (const float*)d_in[8];
    const float* fc2_b = (const float*)d_in[9];
    float* out = (float*)d_out;

    char* ws = (char*)d_ws;
    auto carve = [&](size_t bytes) {
        void* p = (void*)ws;
        ws += (bytes + 255) & ~(size_t)255;
        return p;
    };
    int* indeg = (int*)carve(N_NODES * 4);
    int* rowptr = (int*)carve((N_NODES + 1) * 4);
    int* cursor = (int*)carve(N_NODES * 4);
    float* dinv = (float*)carve(N_NODES * 4);
    int* col = (int*)carve(N_EDGES * 4);
    float* assign = (float*)carve(N_NODES * 2 * 4);
    float* gf = (float*)carve(512 * 4);
    float* napart = (float*)carve(NEWADJ_BLOCKS * 4 * 4);
    float* a1pre = (float*)carve((size_t)N_NODES * 64 * 4);
    ushort_t* zfeat = (ushort_t*)carve((size_t)N_NODES * F_IN * 2);  // dinv-scaled bf16 features
    ushort_t* xa = (ushort_t*)carve((size_t)N_NODES * F_IN * 2);     // aggregated features
    ushort_t* W1t = (ushort_t*)carve(256 * 128 * 2);
    ushort_t* W2t = (ushort_t*)carve(256 * 256 * 2);
    ushort_t* fc1bf = (ushort_t*)carve(64 * 256 * 2);
    ushort_t* bufY = (ushort_t*)carve((size_t)N_NODES * 256 * 2);
    ushort_t* bufH = (ushort_t*)carve((size_t)N_NODES * 256 * 2);

    hipMemsetAsync(indeg, 0, N_NODES * 4, stream);
    hipMemsetAsync(gf, 0, 512 * 4, stream);

    // CSR + prep (prep needs dinv -> after scan)
    hist_kernel<<<N_EDGES / 256, 256, 0, stream>>>(dst, indeg);
    scan_kernel<<<1, 256, 0, stream>>>(indeg, rowptr, cursor, dinv);
    fill_kernel<<<N_EDGES / 256, 256, 0, stream>>>(src, dst, cursor, col);
    prep_kernel<<<2496, 256, 0, stream>>>(features, W1, W2, fc1_w, dinv,
                                          zfeat, W1t, W2t, fc1bf);

    // layer 1 (aggregate-first): xa = Agg(z); h1 = relu(xa@W1 + b1)
    aggregate_wave<1, false><<<N_NODES / 4, 256, 0, stream>>>(
        zfeat, rowptr, col, dinv, (const float*)nullptr, xa);
    gemm_bf16<128, 128, true, false, true, true>
        <<<dim3(H1 / 128, N_NODES / 128), 256, 0, stream>>>(
            xa, W1t, (const float*)nullptr, b1, bufH, F_IN, H1);

    // layer 2: y = (h1@W2)*dinv; h2 = Agg'(y) + b2
    gemm_bf16<128, 128, true, true, false, false>
        <<<dim3(H2 / 128, N_NODES / 128), 256, 0, stream>>>(
            bufH, W2t, dinv, (const float*)nullptr, bufY, H1, H2);
    aggregate_wave<2, true><<<N_NODES / 4, 256, 0, stream>>>(
        bufY, rowptr, col, dinv, b2, bufH);
    // h2 = bufH (bf16)

    // a1pre = h2 @ fc1_w.T
    gemm_bf16<128, 64, false, false, false, false>
        <<<dim3(1, N_NODES / 128), 256, 0, stream>>>(
            bufH, fc1bf, (const float*)nullptr, (const float*)nullptr,
            a1pre, H2, D1);

    assign_kernel<<<N_NODES / 4, 256, 0, stream>>>(a1pre, fc1_b, fc2_w, fc2_b, assign);

    pool_kernel<<<64 + NEWADJ_BLOCKS, 256, 0, stream>>>(
        bufH, assign, src, dst, gf, napart);
    finalize_kernel<<<1, 256, 0, stream>>>(gf, napart, out);
}

// Round 5
// 243.736 us; speedup vs baseline: 1.1225x; 1.1225x over previous
//
#include <hip/hip_runtime.h>
#include <hip/hip_bf16.h>
#include <math.h>

#define N_NODES 16384
#define N_EDGES 524288
#define F_IN 128
#define H1 256
#define H2 256
#define D1 64
#define NEWADJ_BLOCKS 512

typedef __attribute__((ext_vector_type(8))) short short8;
typedef __attribute__((ext_vector_type(4))) float floatx4;
typedef unsigned short ushort_t;
typedef unsigned int uint_t;

__device__ inline float bf2f(ushort_t u) {
    union { uint_t i; float f; } v;
    v.i = ((uint_t)u) << 16;
    return v.f;
}
__device__ inline ushort_t f2bs(float x) {
    __hip_bfloat16 h = __float2bfloat16(x);   // RNE
    return *reinterpret_cast<ushort_t*>(&h);
}

// ---------------- CSR build + weight prep (fused) ----------------
// blocks [0,2048): histogram of dst
// blocks [2048,2176): W1t[n][k] = W1[k][n]       (256x128)
// blocks [2176,2432): W2t[n][k] = W2[k][n]       (256x256)
// blocks [2432,2464): fc1p[kk*64+t] = pack(fc1_w[t][2kk], fc1_w[t][2kk+1])
__global__ __launch_bounds__(256) void histprep_kernel(
    const int* __restrict__ dst, const float* __restrict__ W1,
    const float* __restrict__ W2, const float* __restrict__ fc1_w,
    int* __restrict__ indeg, ushort_t* __restrict__ W1t,
    ushort_t* __restrict__ W2t, uint_t* __restrict__ fc1p) {
    int b = blockIdx.x, t = threadIdx.x;
    if (b < 2048) {
        int e = b * 256 + t;
        atomicAdd(&indeg[dst[e]], 1);
    } else if (b < 2176) {
        int idx = (b - 2048) * 256 + t;      // 0..32767
        int n = idx >> 7, k = idx & 127;
        W1t[idx] = f2bs(W1[k * 256 + n]);
    } else if (b < 2432) {
        int idx = (b - 2176) * 256 + t;      // 0..65535
        int n = idx >> 8, k = idx & 255;
        W2t[idx] = f2bs(W2[k * 256 + n]);
    } else {
        int idx = (b - 2432) * 256 + t;      // 0..8191: kk*64+t
        int tt = idx & 63, kk = idx >> 6;
        uint_t u = (uint_t)f2bs(fc1_w[tt * 256 + 2 * kk]) |
                   ((uint_t)f2bs(fc1_w[tt * 256 + 2 * kk + 1]) << 16);
        fc1p[idx] = u;
    }
}

__global__ void scan_kernel(const int* __restrict__ indeg, int* __restrict__ rowptr,
                            int* __restrict__ cursor, float* __restrict__ dinv) {
    __shared__ int part[256];
    int t = threadIdx.x;
    int base = t * 64;
    int s = 0;
    for (int i = 0; i < 64; ++i) s += indeg[base + i];
    part[t] = s;
    __syncthreads();
    for (int off = 1; off < 256; off <<= 1) {
        int v = part[t];
        int add = (t >= off) ? part[t - off] : 0;
        __syncthreads();
        part[t] = v + add;
        __syncthreads();
    }
    int run = (t == 0) ? 0 : part[t - 1];
    for (int i = 0; i < 64; ++i) {
        int d = indeg[base + i];
        rowptr[base + i] = run;
        cursor[base + i] = run;
        dinv[base + i] = rsqrtf((float)(d + 1));   // +1 self loop
        run += d;
    }
    if (t == 255) rowptr[N_NODES] = run;
}

// blocks [0,2048): CSR fill; blocks [2048,4096): z[n][k] = bf16(feat * dinv[n])
__global__ __launch_bounds__(256) void fillz_kernel(
    const int* __restrict__ src, const int* __restrict__ dst,
    int* __restrict__ cursor, int* __restrict__ col,
    const float* __restrict__ features, const float* __restrict__ dinv,
    ushort_t* __restrict__ z) {
    int b = blockIdx.x, t = threadIdx.x;
    if (b < 2048) {
        int e = b * 256 + t;
        int d = dst[e];
        int p = atomicAdd(&cursor[d], 1);
        col[p] = src[e];
    } else {
        int idx = ((b - 2048) * 256 + t) * 4;
        float di = dinv[idx >> 7];
        float4 v = *(const float4*)&features[idx];
        uint_t lo = (uint_t)f2bs(v.x * di) | ((uint_t)f2bs(v.y * di) << 16);
        uint_t hi = (uint_t)f2bs(v.z * di) | ((uint_t)f2bs(v.w * di) << 16);
        uint2 p; p.x = lo; p.y = hi;
        *(uint2*)&z[idx] = p;
    }
}

// ---------------- bf16 MFMA GEMM with fused epilogue ----------------
template <int BM, int BN, bool OUT_BF16, bool ROWSCALE, bool BIASF, bool RELU>
__global__ __launch_bounds__(256) void gemm_bf16(
    const ushort_t* __restrict__ A, const ushort_t* __restrict__ Bt,
    const float* __restrict__ rowscale, const float* __restrict__ bias,
    void* __restrict__ Cv, int K, int N) {
    constexpr int BK = 32;
    constexpr int LDA = BK + 8;
    constexpr int RM = BM / 2 / 16;
    constexpr int RN = BN / 2 / 16;
    __shared__ ushort_t As[BM * LDA];
    __shared__ ushort_t Bs[BN * LDA];
    const int tid = threadIdx.x;
    const int lane = tid & 63;
    const int wave = tid >> 6;
    const int m = lane & 15;
    const int quad = lane >> 4;
    const int row0 = blockIdx.y * BM;
    const int col0 = blockIdx.x * BN;
    const int wrow0 = (wave >> 1) * (BM / 2);
    const int wcol0 = (wave & 1) * (BN / 2);

    floatx4 acc[RM][RN];
    const floatx4 zero4 = {0.f, 0.f, 0.f, 0.f};
    #pragma unroll
    for (int i = 0; i < RM; ++i)
        #pragma unroll
        for (int j = 0; j < RN; ++j) acc[i][j] = zero4;

    for (int k0 = 0; k0 < K; k0 += BK) {
        __syncthreads();
        #pragma unroll
        for (int i = tid; i < BM * BK / 8; i += 256) {
            int e = i * 8;
            int r = e / BK, c = e % BK;
            *(uint4*)&As[r * LDA + c] =
                *(const uint4*)&A[(size_t)(row0 + r) * K + k0 + c];
        }
        #pragma unroll
        for (int i = tid; i < BN * BK / 8; i += 256) {
            int e = i * 8;
            int r = e / BK, c = e % BK;
            *(uint4*)&Bs[r * LDA + c] =
                *(const uint4*)&Bt[(size_t)(col0 + r) * K + k0 + c];
        }
        __syncthreads();
        short8 a[RM], b[RN];
        #pragma unroll
        for (int i = 0; i < RM; ++i)
            a[i] = *(const short8*)&As[(wrow0 + i * 16 + m) * LDA + quad * 8];
        #pragma unroll
        for (int j = 0; j < RN; ++j)
            b[j] = *(const short8*)&Bs[(wcol0 + j * 16 + m) * LDA + quad * 8];
        #pragma unroll
        for (int i = 0; i < RM; ++i)
            #pragma unroll
            for (int j = 0; j < RN; ++j)
                acc[i][j] = __builtin_amdgcn_mfma_f32_16x16x32_bf16(
                    a[i], b[j], acc[i][j], 0, 0, 0);
    }

    ushort_t* Cb = (ushort_t*)Cv;
    float* Cf = (float*)Cv;
    #pragma unroll
    for (int i = 0; i < RM; ++i) {
        int rbase = row0 + wrow0 + i * 16 + quad * 4;
        float rs4[4];
        #pragma unroll
        for (int r = 0; r < 4; ++r)
            rs4[r] = ROWSCALE ? rowscale[rbase + r] : 1.0f;
        #pragma unroll
        for (int j = 0; j < RN; ++j) {
            int cg = col0 + wcol0 + j * 16 + m;
            float bv = BIASF ? bias[cg] : 0.0f;
            #pragma unroll
            for (int r = 0; r < 4; ++r) {
                float v = acc[i][j][r] * rs4[r] + bv;
                if (RELU) v = fmaxf(v, 0.0f);
                if (OUT_BF16) Cb[(size_t)(rbase + r) * N + cg] = f2bs(v);
                else          Cf[(size_t)(rbase + r) * N + cg] = v;
            }
        }
    }
}

// ---------------- layer-1 aggregation (wave/node, scalar indices, unroll-8) ----
// xa[d][f] = bf16( z[d][f] + sum_nbr z[s][f] )      (z already dinv-prescaled;
// trailing *dinv[d] applied here)
__global__ __launch_bounds__(256) void aggregate1(
    const ushort_t* __restrict__ y, const int* __restrict__ rowptr,
    const int* __restrict__ col, const float* __restrict__ dinv,
    ushort_t* __restrict__ out) {
    const int node = __builtin_amdgcn_readfirstlane(
        (int)((blockIdx.x * 256 + threadIdx.x) >> 6));
    const int lane = threadIdx.x & 63;
    const int foff = lane * 2;
    uint_t self = *(const uint_t*)&y[(size_t)node * 128 + foff];
    float a0 = bf2f((ushort_t)(self & 0xffff));
    float a1 = bf2f((ushort_t)(self >> 16));
    const int s1 = rowptr[node + 1];
    int base = rowptr[node];
    for (; base + 8 <= s1; base += 8) {
        uint_t uu[8];
        #pragma unroll
        for (int q = 0; q < 8; ++q) {
            int j = col[base + q];                       // wave-uniform
            uu[q] = *(const uint_t*)&y[(size_t)j * 128 + foff];
        }
        #pragma unroll
        for (int q = 0; q < 8; ++q) {
            a0 += bf2f((ushort_t)(uu[q] & 0xffff));
            a1 += bf2f((ushort_t)(uu[q] >> 16));
        }
    }
    for (; base < s1; ++base) {
        int j = col[base];
        uint_t u = *(const uint_t*)&y[(size_t)j * 128 + foff];
        a0 += bf2f((ushort_t)(u & 0xffff));
        a1 += bf2f((ushort_t)(u >> 16));
    }
    float di = dinv[node];
    uint_t packed = (uint_t)f2bs(a0 * di) | ((uint_t)f2bs(a1 * di) << 16);
    *(uint_t*)&out[(size_t)node * 128 + foff] = packed;
}

// ---------------- layer-2 aggregation + fc1 + assignment (fused) ----------
// h2[d] = Agg'(y)[d] + b2 ; a = tanh(h2 . fc1_w[t] + fc1_b[t]) ;
// assign[d] = softmax(a @ fc2_w.T + fc2_b)
__global__ __launch_bounds__(256) void agg2_assign(
    const ushort_t* __restrict__ y, const int* __restrict__ rowptr,
    const int* __restrict__ col, const float* __restrict__ dinv,
    const float* __restrict__ b2, const uint_t* __restrict__ fc1p,
    const float* __restrict__ fc1_b, const float* __restrict__ fc2_w,
    const float* __restrict__ fc2_b,
    ushort_t* __restrict__ h2out, float* __restrict__ assign) {
    __shared__ float sh[4][256];
    const int node = __builtin_amdgcn_readfirstlane(
        (int)((blockIdx.x * 256 + threadIdx.x) >> 6));
    const int wave = threadIdx.x >> 6;
    const int lane = threadIdx.x & 63;
    const int foff = lane * 4;
    float a0, a1, a2, a3;
    {
        uint2 u = *(const uint2*)&y[(size_t)node * 256 + foff];
        a0 = bf2f((ushort_t)(u.x & 0xffff));
        a1 = bf2f((ushort_t)(u.x >> 16));
        a2 = bf2f((ushort_t)(u.y & 0xffff));
        a3 = bf2f((ushort_t)(u.y >> 16));
    }
    const int s1 = rowptr[node + 1];
    int base = rowptr[node];
    for (; base + 8 <= s1; base += 8) {
        uint2 uu[8];
        #pragma unroll
        for (int q = 0; q < 8; ++q) {
            int j = col[base + q];                       // wave-uniform
            uu[q] = *(const uint2*)&y[(size_t)j * 256 + foff];
        }
        #pragma unroll
        for (int q = 0; q < 8; ++q) {
            a0 += bf2f((ushort_t)(uu[q].x & 0xffff));
            a1 += bf2f((ushort_t)(uu[q].x >> 16));
            a2 += bf2f((ushort_t)(uu[q].y & 0xffff));
            a3 += bf2f((ushort_t)(uu[q].y >> 16));
        }
    }
    for (; base < s1; ++base) {
        int j = col[base];
        uint2 u = *(const uint2*)&y[(size_t)j * 256 + foff];
        a0 += bf2f((ushort_t)(u.x & 0xffff));
        a1 += bf2f((ushort_t)(u.x >> 16));
        a2 += bf2f((ushort_t)(u.y & 0xffff));
        a3 += bf2f((ushort_t)(u.y >> 16));
    }
    float di = dinv[node];
    float v0 = a0 * di + b2[foff + 0];
    float v1 = a1 * di + b2[foff + 1];
    float v2 = a2 * di + b2[foff + 2];
    float v3 = a3 * di + b2[foff + 3];
    // h2 to global (bf16)
    uint2 pk;
    pk.x = (uint_t)f2bs(v0) | ((uint_t)f2bs(v1) << 16);
    pk.y = (uint_t)f2bs(v2) | ((uint_t)f2bs(v3) << 16);
    *(uint2*)&h2out[(size_t)node * 256 + foff] = pk;
    // h2 row into this wave's LDS slab (fp32); same-wave read below, no barrier
    sh[wave][foff + 0] = v0;
    sh[wave][foff + 1] = v1;
    sh[wave][foff + 2] = v2;
    sh[wave][foff + 3] = v3;
    // lane t computes a1[t] = tanh(sum_k h2[k]*fc1_w[t][k] + fc1_b[t])
    float accd = 0.f;
    #pragma unroll 4
    for (int kk = 0; kk < 128; ++kk) {
        uint_t w = fc1p[kk * 64 + lane];                 // coalesced, L1-hot
        float s0 = sh[wave][2 * kk];                     // broadcast
        float s0b = sh[wave][2 * kk + 1];
        accd += s0 * bf2f((ushort_t)(w & 0xffff));
        accd += s0b * bf2f((ushort_t)(w >> 16));
    }
    float av = tanhf(accd + fc1_b[lane]);
    float p0 = av * fc2_w[lane];
    float p1 = av * fc2_w[64 + lane];
    #pragma unroll
    for (int off = 32; off; off >>= 1) {
        p0 += __shfl_down(p0, off);
        p1 += __shfl_down(p1, off);
    }
    if (lane == 0) {
        p0 += fc2_b[0];
        p1 += fc2_b[1];
        float mx = fmaxf(p0, p1);
        float e0 = expf(p0 - mx), e1 = expf(p1 - mx);
        float inv = 1.0f / (e0 + e1);
        float2 as; as.x = e0 * inv; as.y = e1 * inv;
        *(float2*)&assign[node * 2] = as;
    }
}

// ---------------- fused pooled reductions ----------------
// blocks [0,256): gf[k][f] = sum over 64 nodes of assign[n][k]*h2[n][f]
// blocks [256,256+NEWADJ_BLOCKS): new_adj partials
__global__ __launch_bounds__(256) void pool_kernel(
    const ushort_t* __restrict__ h2, const float* __restrict__ assign,
    const int* __restrict__ src, const int* __restrict__ dst,
    float* __restrict__ gf, float* __restrict__ part) {
    if (blockIdx.x < 256) {
        __shared__ float as0[64], as1[64];
        int f = threadIdx.x;
        int n0 = blockIdx.x * 64;
        if (f < 64) {
            float2 a = *(const float2*)&assign[(n0 + f) * 2];
            as0[f] = a.x; as1[f] = a.y;
        }
        __syncthreads();
        float acc0 = 0.f, acc1 = 0.f;
        for (int i = 0; i < 64; ++i) {
            float h = bf2f(h2[(size_t)(n0 + i) * 256 + f]);
            acc0 += as0[i] * h;
            acc1 += as1[i] * h;
        }
        atomicAdd(&gf[f], acc0);
        atomicAdd(&gf[256 + f], acc1);
    } else {
        __shared__ float red[4][4];
        int blk = blockIdx.x - 256;
        float a00 = 0.f, a01 = 0.f, a10 = 0.f, a11 = 0.f;
        for (int e = blk * 256 + threadIdx.x; e < N_EDGES;
             e += NEWADJ_BLOCKS * 256) {
            int s = src[e], d = dst[e];
            float s0 = assign[s * 2], s1 = assign[s * 2 + 1];
            float d0 = assign[d * 2], d1 = assign[d * 2 + 1];
            a00 += s0 * d0; a01 += s0 * d1; a10 += s1 * d0; a11 += s1 * d1;
        }
        #pragma unroll
        for (int off = 32; off; off >>= 1) {
            a00 += __shfl_down(a00, off);
            a01 += __shfl_down(a01, off);
            a10 += __shfl_down(a10, off);
            a11 += __shfl_down(a11, off);
        }
        int wave = threadIdx.x >> 6;
        if ((threadIdx.x & 63) == 0) {
            red[wave][0] = a00; red[wave][1] = a01;
            red[wave][2] = a10; red[wave][3] = a11;
        }
        __syncthreads();
        if (threadIdx.x < 4) {
            float v = red[0][threadIdx.x] + red[1][threadIdx.x] +
                      red[2][threadIdx.x] + red[3][threadIdx.x];
            part[blk * 4 + threadIdx.x] = v;
        }
    }
}

__global__ __launch_bounds__(256) void finalize_kernel(
    const float* __restrict__ gf, const float* __restrict__ part,
    float* __restrict__ out) {
    __shared__ float na[4];
    int t = threadIdx.x;
    int wave = t >> 6, lane = t & 63;
    float acc = 0.f;
    for (int i = lane; i < NEWADJ_BLOCKS; i += 64) acc += part[i * 4 + wave];
    #pragma unroll
    for (int off = 32; off; off >>= 1) acc += __shfl_down(acc, off);
    if (lane == 0) na[wave] = acc;
    __syncthreads();
    float g0 = gf[t], g1 = gf[256 + t];
    out[t] = 0.5f * (g0 + g1);
    out[256 + t] = fminf(fmaxf(g0, -100.f), 100.f);
    out[512 + t] = fminf(fmaxf(g1, -100.f), 100.f);
    if (t == 0) {
        float n00 = na[0], n01 = na[1], n10 = na[2], n11 = na[3];
        float den0 = fmaxf(fabsf(n00) + fabsf(n01), 1e-12f);
        float den1 = fmaxf(fabsf(n10) + fabsf(n11), 1e-12f);
        float x0 = n00 / den0 - 1.0f;
        float x1 = n11 / den1 - 1.0f;
        out[768] = 0.5f * (x0 * x0 + x1 * x1);
    }
}

// ---------------- launch ----------------

extern "C" void kernel_launch(void* const* d_in, const int* in_sizes, int n_in,
                              void* d_out, int out_size, void* d_ws, size_t ws_size,
                              hipStream_t stream) {
    const float* features = (const float*)d_in[0];
    const int* edges = (const int*)d_in[1];
    const int* src = edges;
    const int* dst = edges + N_EDGES;
    const float* W1 = (const float*)d_in[2];
    const float* b1 = (const float*)d_in[3];
    const float* W2 = (const float*)d_in[4];
    const float* b2 = (const float*)d_in[5];
    const float* fc1_w = (const float*)d_in[6];
    const float* fc1_b = (const float*)d_in[7];
    const float* fc2_w = (const float*)d_in[8];
    const float* fc2_b = (const float*)d_in[9];
    float* out = (float*)d_out;

    char* ws = (char*)d_ws;
    auto carve = [&](size_t bytes) {
        void* p = (void*)ws;
        ws += (bytes + 255) & ~(size_t)255;
        return p;
    };
    // indeg and gf adjacent -> one memset covers both
    int* indeg = (int*)carve(N_NODES * 4);           // 65536 B
    float* gf = (float*)carve(512 * 4);              // 2048 B
    int* rowptr = (int*)carve((N_NODES + 1) * 4);
    int* cursor = (int*)carve(N_NODES * 4);
    float* dinv = (float*)carve(N_NODES * 4);
    int* col = (int*)carve(N_EDGES * 4);
    float* assign = (float*)carve(N_NODES * 2 * 4);
    float* napart = (float*)carve(NEWADJ_BLOCKS * 4 * 4);
    uint_t* fc1p = (uint_t*)carve(128 * 64 * 4);
    ushort_t* zfeat = (ushort_t*)carve((size_t)N_NODES * F_IN * 2);
    ushort_t* xa = (ushort_t*)carve((size_t)N_NODES * F_IN * 2);
    ushort_t* W1t = (ushort_t*)carve(256 * 128 * 2);
    ushort_t* W2t = (ushort_t*)carve(256 * 256 * 2);
    ushort_t* bufY = (ushort_t*)carve((size_t)N_NODES * 256 * 2);
    ushort_t* bufH = (ushort_t*)carve((size_t)N_NODES * 256 * 2);

    hipMemsetAsync(indeg, 0, N_NODES * 4 + 512 * 4, stream);  // indeg + gf

    histprep_kernel<<<2464, 256, 0, stream>>>(dst, W1, W2, fc1_w,
                                              indeg, W1t, W2t, fc1p);
    scan_kernel<<<1, 256, 0, stream>>>(indeg, rowptr, cursor, dinv);
    fillz_kernel<<<4096, 256, 0, stream>>>(src, dst, cursor, col,
                                           features, dinv, zfeat);

    // layer 1 (aggregate-first): xa = dinv*Agg(z); h1 = relu(xa@W1 + b1)
    aggregate1<<<N_NODES / 4, 256, 0, stream>>>(zfeat, rowptr, col, dinv, xa);
    gemm_bf16<128, 128, true, false, true, true>
        <<<dim3(H1 / 128, N_NODES / 128), 256, 0, stream>>>(
            xa, W1t, (const float*)nullptr, b1, bufH, F_IN, H1);

    // layer 2: y = (h1@W2)*dinv
    gemm_bf16<128, 128, true, true, false, false>
        <<<dim3(H2 / 128, N_NODES / 128), 256, 0, stream>>>(
            bufH, W2t, dinv, (const float*)nullptr, bufY, H1, H2);

    // h2 = Agg'(y)+b2, fused with fc1+tanh+fc2+softmax -> assign
    agg2_assign<<<N_NODES / 4, 256, 0, stream>>>(
        bufY, rowptr, col, dinv, b2, fc1p, fc1_b, fc2_w, fc2_b, bufH, assign);

    pool_kernel<<<256 + NEWADJ_BLOCKS, 256, 0, stream>>>(
        bufH, assign, src, dst, gf, napart);
    finalize_kernel<<<1, 256, 0, stream>>>(gf, napart, out);
}

// Round 6
// 236.757 us; speedup vs baseline: 1.1556x; 1.0295x over previous
//
#include <hip/hip_runtime.h>
#include <hip/hip_bf16.h>
#include <math.h>

#define N_NODES 16384
#define N_EDGES 524288
#define F_IN 128
#define H1 256
#define H2 256
#define D1 64
#define NEWADJ_BLOCKS 512

typedef __attribute__((ext_vector_type(8))) short short8;
typedef __attribute__((ext_vector_type(4))) float floatx4;
typedef unsigned short ushort_t;
typedef unsigned int uint_t;

__device__ inline float bf2f(ushort_t u) {
    union { uint_t i; float f; } v;
    v.i = ((uint_t)u) << 16;
    return v.f;
}
__device__ inline ushort_t f2bs(float x) {
    __hip_bfloat16 h = __float2bfloat16(x);   // RNE
    return *reinterpret_cast<ushort_t*>(&h);
}

// ---------------- CSR build + weight prep (fused) ----------------
// blocks [0,2048): histogram of dst
// blocks [2048,2176): W1t[n][k] = W1[k][n]       (256x128)
// blocks [2176,2432): W2t[n][k] = W2[k][n]       (256x256)
// blocks [2432,2496): fc1bf = bf16(fc1_w)        (64x256, already [out][k])
__global__ __launch_bounds__(256) void histprep_kernel(
    const int* __restrict__ dst, const float* __restrict__ W1,
    const float* __restrict__ W2, const float* __restrict__ fc1_w,
    int* __restrict__ indeg, ushort_t* __restrict__ W1t,
    ushort_t* __restrict__ W2t, ushort_t* __restrict__ fc1bf) {
    int b = blockIdx.x, t = threadIdx.x;
    if (b < 2048) {
        int e = b * 256 + t;
        atomicAdd(&indeg[dst[e]], 1);
    } else if (b < 2176) {
        int idx = (b - 2048) * 256 + t;      // 0..32767
        int n = idx >> 7, k = idx & 127;
        W1t[idx] = f2bs(W1[k * 256 + n]);
    } else if (b < 2432) {
        int idx = (b - 2176) * 256 + t;      // 0..65535
        int n = idx >> 8, k = idx & 255;
        W2t[idx] = f2bs(W2[k * 256 + n]);
    } else {
        int idx = (b - 2432) * 256 + t;      // 0..16383
        fc1bf[idx] = f2bs(fc1_w[idx]);
    }
}

__global__ void scan_kernel(const int* __restrict__ indeg, int* __restrict__ rowptr,
                            int* __restrict__ cursor, float* __restrict__ dinv) {
    __shared__ int part[256];
    int t = threadIdx.x;
    int base = t * 64;
    int s = 0;
    for (int i = 0; i < 64; ++i) s += indeg[base + i];
    part[t] = s;
    __syncthreads();
    for (int off = 1; off < 256; off <<= 1) {
        int v = part[t];
        int add = (t >= off) ? part[t - off] : 0;
        __syncthreads();
        part[t] = v + add;
        __syncthreads();
    }
    int run = (t == 0) ? 0 : part[t - 1];
    for (int i = 0; i < 64; ++i) {
        int d = indeg[base + i];
        rowptr[base + i] = run;
        cursor[base + i] = run;
        dinv[base + i] = rsqrtf((float)(d + 1));   // +1 self loop
        run += d;
    }
    if (t == 255) rowptr[N_NODES] = run;
}

// blocks [0,2048): CSR fill; blocks [2048,4096): z[n][k] = bf16(feat * dinv[n])
__global__ __launch_bounds__(256) void fillz_kernel(
    const int* __restrict__ src, const int* __restrict__ dst,
    int* __restrict__ cursor, int* __restrict__ col,
    const float* __restrict__ features, const float* __restrict__ dinv,
    ushort_t* __restrict__ z) {
    int b = blockIdx.x, t = threadIdx.x;
    if (b < 2048) {
        int e = b * 256 + t;
        int d = dst[e];
        int p = atomicAdd(&cursor[d], 1);
        col[p] = src[e];
    } else {
        int idx = ((b - 2048) * 256 + t) * 4;
        float di = dinv[idx >> 7];
        float4 v = *(const float4*)&features[idx];
        uint_t lo = (uint_t)f2bs(v.x * di) | ((uint_t)f2bs(v.y * di) << 16);
        uint_t hi = (uint_t)f2bs(v.z * di) | ((uint_t)f2bs(v.w * di) << 16);
        uint2 p; p.x = lo; p.y = hi;
        *(uint2*)&z[idx] = p;
    }
}

// ---------------- bf16 MFMA GEMM with fused epilogue ----------------
template <int BM, int BN, bool OUT_BF16, bool ROWSCALE, bool BIASF, bool RELU>
__global__ __launch_bounds__(256) void gemm_bf16(
    const ushort_t* __restrict__ A, const ushort_t* __restrict__ Bt,
    const float* __restrict__ rowscale, const float* __restrict__ bias,
    void* __restrict__ Cv, int K, int N) {
    constexpr int BK = 32;
    constexpr int LDA = BK + 8;
    constexpr int RM = BM / 2 / 16;
    constexpr int RN = BN / 2 / 16;
    __shared__ ushort_t As[BM * LDA];
    __shared__ ushort_t Bs[BN * LDA];
    const int tid = threadIdx.x;
    const int lane = tid & 63;
    const int wave = tid >> 6;
    const int m = lane & 15;
    const int quad = lane >> 4;
    const int row0 = blockIdx.y * BM;
    const int col0 = blockIdx.x * BN;
    const int wrow0 = (wave >> 1) * (BM / 2);
    const int wcol0 = (wave & 1) * (BN / 2);

    floatx4 acc[RM][RN];
    const floatx4 zero4 = {0.f, 0.f, 0.f, 0.f};
    #pragma unroll
    for (int i = 0; i < RM; ++i)
        #pragma unroll
        for (int j = 0; j < RN; ++j) acc[i][j] = zero4;

    for (int k0 = 0; k0 < K; k0 += BK) {
        __syncthreads();
        #pragma unroll
        for (int i = tid; i < BM * BK / 8; i += 256) {
            int e = i * 8;
            int r = e / BK, c = e % BK;
            *(uint4*)&As[r * LDA + c] =
                *(const uint4*)&A[(size_t)(row0 + r) * K + k0 + c];
        }
        #pragma unroll
        for (int i = tid; i < BN * BK / 8; i += 256) {
            int e = i * 8;
            int r = e / BK, c = e % BK;
            *(uint4*)&Bs[r * LDA + c] =
                *(const uint4*)&Bt[(size_t)(col0 + r) * K + k0 + c];
        }
        __syncthreads();
        short8 a[RM], b[RN];
        #pragma unroll
        for (int i = 0; i < RM; ++i)
            a[i] = *(const short8*)&As[(wrow0 + i * 16 + m) * LDA + quad * 8];
        #pragma unroll
        for (int j = 0; j < RN; ++j)
            b[j] = *(const short8*)&Bs[(wcol0 + j * 16 + m) * LDA + quad * 8];
        #pragma unroll
        for (int i = 0; i < RM; ++i)
            #pragma unroll
            for (int j = 0; j < RN; ++j)
                acc[i][j] = __builtin_amdgcn_mfma_f32_16x16x32_bf16(
                    a[i], b[j], acc[i][j], 0, 0, 0);
    }

    ushort_t* Cb = (ushort_t*)Cv;
    float* Cf = (float*)Cv;
    #pragma unroll
    for (int i = 0; i < RM; ++i) {
        int rbase = row0 + wrow0 + i * 16 + quad * 4;
        float rs4[4];
        #pragma unroll
        for (int r = 0; r < 4; ++r)
            rs4[r] = ROWSCALE ? rowscale[rbase + r] : 1.0f;
        #pragma unroll
        for (int j = 0; j < RN; ++j) {
            int cg = col0 + wcol0 + j * 16 + m;
            float bv = BIASF ? bias[cg] : 0.0f;
            #pragma unroll
            for (int r = 0; r < 4; ++r) {
                float v = acc[i][j][r] * rs4[r] + bv;
                if (RELU) v = fmaxf(v, 0.0f);
                if (OUT_BF16) Cb[(size_t)(rbase + r) * N + cg] = f2bs(v);
                else          Cf[(size_t)(rbase + r) * N + cg] = v;
            }
        }
    }
}

// ------- fc1 GEMM + tanh + fc2 + softmax fused: assign per node -------
// A = h2 [16384][256] bf16, Bt = fc1bf [64][256] bf16.
// Each block: 128 nodes x 64 outputs -> full a1 rows -> softmax in-block.
__global__ __launch_bounds__(256) void gemm_assign(
    const ushort_t* __restrict__ A, const ushort_t* __restrict__ Bt,
    const float* __restrict__ fc1_b, const float* __restrict__ fc2_w,
    const float* __restrict__ fc2_b, float* __restrict__ assign) {
    constexpr int BM = 128, BN = 64, BK = 32, LDA = BK + 8;
    constexpr int RM = 4, RN = 2;
    __shared__ ushort_t As[BM * LDA];
    __shared__ ushort_t Bs[BN * LDA];
    __shared__ float sha[BM][BN + 1];     // +1 pad: read phase 2-way (free)
    const int tid = threadIdx.x;
    const int lane = tid & 63;
    const int wave = tid >> 6;
    const int m = lane & 15;
    const int quad = lane >> 4;
    const int row0 = blockIdx.x * BM;
    const int wrow0 = (wave >> 1) * 64;
    const int wcol0 = (wave & 1) * 32;

    floatx4 acc[RM][RN];
    const floatx4 zero4 = {0.f, 0.f, 0.f, 0.f};
    #pragma unroll
    for (int i = 0; i < RM; ++i)
        #pragma unroll
        for (int j = 0; j < RN; ++j) acc[i][j] = zero4;

    for (int k0 = 0; k0 < 256; k0 += BK) {
        __syncthreads();
        #pragma unroll
        for (int i = tid; i < BM * BK / 8; i += 256) {
            int e = i * 8;
            int r = e / BK, c = e % BK;
            *(uint4*)&As[r * LDA + c] =
                *(const uint4*)&A[(size_t)(row0 + r) * 256 + k0 + c];
        }
        {
            int e = tid * 8;
            int r = e / BK, c = e % BK;
            *(uint4*)&Bs[r * LDA + c] =
                *(const uint4*)&Bt[(size_t)r * 256 + k0 + c];
        }
        __syncthreads();
        short8 a[RM], b[RN];
        #pragma unroll
        for (int i = 0; i < RM; ++i)
            a[i] = *(const short8*)&As[(wrow0 + i * 16 + m) * LDA + quad * 8];
        #pragma unroll
        for (int j = 0; j < RN; ++j)
            b[j] = *(const short8*)&Bs[(wcol0 + j * 16 + m) * LDA + quad * 8];
        #pragma unroll
        for (int i = 0; i < RM; ++i)
            #pragma unroll
            for (int j = 0; j < RN; ++j)
                acc[i][j] = __builtin_amdgcn_mfma_f32_16x16x32_bf16(
                    a[i], b[j], acc[i][j], 0, 0, 0);
    }

    // tanh(acc + fc1_b) -> LDS
    #pragma unroll
    for (int i = 0; i < RM; ++i) {
        int rl = wrow0 + i * 16 + quad * 4;
        #pragma unroll
        for (int j = 0; j < RN; ++j) {
            int cg = wcol0 + j * 16 + m;
            float bv = fc1_b[cg];
            #pragma unroll
            for (int r = 0; r < 4; ++r)
                sha[rl + r][cg] = tanhf(acc[i][j][r] + bv);
        }
    }
    __syncthreads();
    // per node: 64-dot with fc2 + softmax
    if (tid < BM) {
        float p0 = fc2_b[0], p1 = fc2_b[1];
        #pragma unroll 8
        for (int t = 0; t < 64; ++t) {
            float a = sha[tid][t];
            p0 += a * fc2_w[t];
            p1 += a * fc2_w[64 + t];
        }
        float mx = fmaxf(p0, p1);
        float e0 = expf(p0 - mx), e1 = expf(p1 - mx);
        float inv = 1.0f / (e0 + e1);
        float2 as; as.x = e0 * inv; as.y = e1 * inv;
        *(float2*)&assign[(row0 + tid) * 2] = as;
    }
}

// ---------------- layer-1 aggregation (wave/node, scalar indices, unroll-8) ----
__global__ __launch_bounds__(256) void aggregate1(
    const ushort_t* __restrict__ y, const int* __restrict__ rowptr,
    const int* __restrict__ col, const float* __restrict__ dinv,
    ushort_t* __restrict__ out) {
    const int node = __builtin_amdgcn_readfirstlane(
        (int)((blockIdx.x * 256 + threadIdx.x) >> 6));
    const int lane = threadIdx.x & 63;
    const int foff = lane * 2;
    uint_t self = *(const uint_t*)&y[(size_t)node * 128 + foff];
    float a0 = bf2f((ushort_t)(self & 0xffff));
    float a1 = bf2f((ushort_t)(self >> 16));
    const int s1 = rowptr[node + 1];
    int base = rowptr[node];
    for (; base + 8 <= s1; base += 8) {
        uint_t uu[8];
        #pragma unroll
        for (int q = 0; q < 8; ++q) {
            int j = col[base + q];                       // wave-uniform
            uu[q] = *(const uint_t*)&y[(size_t)j * 128 + foff];
        }
        #pragma unroll
        for (int q = 0; q < 8; ++q) {
            a0 += bf2f((ushort_t)(uu[q] & 0xffff));
            a1 += bf2f((ushort_t)(uu[q] >> 16));
        }
    }
    for (; base < s1; ++base) {
        int j = col[base];
        uint_t u = *(const uint_t*)&y[(size_t)j * 128 + foff];
        a0 += bf2f((ushort_t)(u & 0xffff));
        a1 += bf2f((ushort_t)(u >> 16));
    }
    float di = dinv[node];
    uint_t packed = (uint_t)f2bs(a0 * di) | ((uint_t)f2bs(a1 * di) << 16);
    *(uint_t*)&out[(size_t)node * 128 + foff] = packed;
}

// ---------------- layer-2 aggregation (slim: gather + bias only) ----------
__global__ __launch_bounds__(256) void aggregate2(
    const ushort_t* __restrict__ y, const int* __restrict__ rowptr,
    const int* __restrict__ col, const float* __restrict__ dinv,
    const float* __restrict__ b2, ushort_t* __restrict__ h2out) {
    const int node = __builtin_amdgcn_readfirstlane(
        (int)((blockIdx.x * 256 + threadIdx.x) >> 6));
    const int lane = threadIdx.x & 63;
    const int foff = lane * 4;
    float a0, a1, a2, a3;
    {
        uint2 u = *(const uint2*)&y[(size_t)node * 256 + foff];
        a0 = bf2f((ushort_t)(u.x & 0xffff));
        a1 = bf2f((ushort_t)(u.x >> 16));
        a2 = bf2f((ushort_t)(u.y & 0xffff));
        a3 = bf2f((ushort_t)(u.y >> 16));
    }
    const int s1 = rowptr[node + 1];
    int base = rowptr[node];
    for (; base + 8 <= s1; base += 8) {
        uint2 uu[8];
        #pragma unroll
        for (int q = 0; q < 8; ++q) {
            int j = col[base + q];                       // wave-uniform
            uu[q] = *(const uint2*)&y[(size_t)j * 256 + foff];
        }
        #pragma unroll
        for (int q = 0; q < 8; ++q) {
            a0 += bf2f((ushort_t)(uu[q].x & 0xffff));
            a1 += bf2f((ushort_t)(uu[q].x >> 16));
            a2 += bf2f((ushort_t)(uu[q].y & 0xffff));
            a3 += bf2f((ushort_t)(uu[q].y >> 16));
        }
    }
    for (; base < s1; ++base) {
        int j = col[base];
        uint2 u = *(const uint2*)&y[(size_t)j * 256 + foff];
        a0 += bf2f((ushort_t)(u.x & 0xffff));
        a1 += bf2f((ushort_t)(u.x >> 16));
        a2 += bf2f((ushort_t)(u.y & 0xffff));
        a3 += bf2f((ushort_t)(u.y >> 16));
    }
    float di = dinv[node];
    float v0 = a0 * di + b2[foff + 0];
    float v1 = a1 * di + b2[foff + 1];
    float v2 = a2 * di + b2[foff + 2];
    float v3 = a3 * di + b2[foff + 3];
    uint2 pk;
    pk.x = (uint_t)f2bs(v0) | ((uint_t)f2bs(v1) << 16);
    pk.y = (uint_t)f2bs(v2) | ((uint_t)f2bs(v3) << 16);
    *(uint2*)&h2out[(size_t)node * 256 + foff] = pk;
}

// ---------------- fused pooled reductions ----------------
// blocks [0,256): gf[k][f] = sum over 64 nodes of assign[n][k]*h2[n][f]
// blocks [256,256+NEWADJ_BLOCKS): new_adj partials
__global__ __launch_bounds__(256) void pool_kernel(
    const ushort_t* __restrict__ h2, const float* __restrict__ assign,
    const int* __restrict__ src, const int* __restrict__ dst,
    float* __restrict__ gf, float* __restrict__ part) {
    if (blockIdx.x < 256) {
        __shared__ float as0[64], as1[64];
        int f = threadIdx.x;
        int n0 = blockIdx.x * 64;
        if (f < 64) {
            float2 a = *(const float2*)&assign[(n0 + f) * 2];
            as0[f] = a.x; as1[f] = a.y;
        }
        __syncthreads();
        float acc0 = 0.f, acc1 = 0.f;
        for (int i = 0; i < 64; ++i) {
            float h = bf2f(h2[(size_t)(n0 + i) * 256 + f]);
            acc0 += as0[i] * h;
            acc1 += as1[i] * h;
        }
        atomicAdd(&gf[f], acc0);
        atomicAdd(&gf[256 + f], acc1);
    } else {
        __shared__ float red[4][4];
        int blk = blockIdx.x - 256;
        float a00 = 0.f, a01 = 0.f, a10 = 0.f, a11 = 0.f;
        for (int e = blk * 256 + threadIdx.x; e < N_EDGES;
             e += NEWADJ_BLOCKS * 256) {
            int s = src[e], d = dst[e];
            float s0 = assign[s * 2], s1 = assign[s * 2 + 1];
            float d0 = assign[d * 2], d1 = assign[d * 2 + 1];
            a00 += s0 * d0; a01 += s0 * d1; a10 += s1 * d0; a11 += s1 * d1;
        }
        #pragma unroll
        for (int off = 32; off; off >>= 1) {
            a00 += __shfl_down(a00, off);
            a01 += __shfl_down(a01, off);
            a10 += __shfl_down(a10, off);
            a11 += __shfl_down(a11, off);
        }
        int wave = threadIdx.x >> 6;
        if ((threadIdx.x & 63) == 0) {
            red[wave][0] = a00; red[wave][1] = a01;
            red[wave][2] = a10; red[wave][3] = a11;
        }
        __syncthreads();
        if (threadIdx.x < 4) {
            float v = red[0][threadIdx.x] + red[1][threadIdx.x] +
                      red[2][threadIdx.x] + red[3][threadIdx.x];
            part[blk * 4 + threadIdx.x] = v;
        }
    }
}

__global__ __launch_bounds__(256) void finalize_kernel(
    const float* __restrict__ gf, const float* __restrict__ part,
    float* __restrict__ out) {
    __shared__ float na[4];
    int t = threadIdx.x;
    int wave = t >> 6, lane = t & 63;
    float acc = 0.f;
    for (int i = lane; i < NEWADJ_BLOCKS; i += 64) acc += part[i * 4 + wave];
    #pragma unroll
    for (int off = 32; off; off >>= 1) acc += __shfl_down(acc, off);
    if (lane == 0) na[wave] = acc;
    __syncthreads();
    float g0 = gf[t], g1 = gf[256 + t];
    out[t] = 0.5f * (g0 + g1);
    out[256 + t] = fminf(fmaxf(g0, -100.f), 100.f);
    out[512 + t] = fminf(fmaxf(g1, -100.f), 100.f);
    if (t == 0) {
        float n00 = na[0], n01 = na[1], n10 = na[2], n11 = na[3];
        float den0 = fmaxf(fabsf(n00) + fabsf(n01), 1e-12f);
        float den1 = fmaxf(fabsf(n10) + fabsf(n11), 1e-12f);
        float x0 = n00 / den0 - 1.0f;
        float x1 = n11 / den1 - 1.0f;
        out[768] = 0.5f * (x0 * x0 + x1 * x1);
    }
}

// ---------------- launch ----------------

extern "C" void kernel_launch(void* const* d_in, const int* in_sizes, int n_in,
                              void* d_out, int out_size, void* d_ws, size_t ws_size,
                              hipStream_t stream) {
    const float* features = (const float*)d_in[0];
    const int* edges = (const int*)d_in[1];
    const int* src = edges;
    const int* dst = edges + N_EDGES;
    const float* W1 = (const float*)d_in[2];
    const float* b1 = (const float*)d_in[3];
    const float* W2 = (const float*)d_in[4];
    const float* b2 = (const float*)d_in[5];
    const float* fc1_w = (const float*)d_in[6];
    const float* fc1_b = (const float*)d_in[7];
    const float* fc2_w = (const float*)d_in[8];
    const float* fc2_b = (const float*)d_in[9];
    float* out = (float*)d_out;

    char* ws = (char*)d_ws;
    auto carve = [&](size_t bytes) {
        void* p = (void*)ws;
        ws += (bytes + 255) & ~(size_t)255;
        return p;
    };
    // indeg and gf adjacent -> one memset covers both
    int* indeg = (int*)carve(N_NODES * 4);           // 65536 B
    float* gf = (float*)carve(512 * 4);              // 2048 B
    int* rowptr = (int*)carve((N_NODES + 1) * 4);
    int* cursor = (int*)carve(N_NODES * 4);
    float* dinv = (float*)carve(N_NODES * 4);
    int* col = (int*)carve(N_EDGES * 4);
    float* assign = (float*)carve(N_NODES * 2 * 4);
    float* napart = (float*)carve(NEWADJ_BLOCKS * 4 * 4);
    ushort_t* fc1bf = (ushort_t*)carve(64 * 256 * 2);
    ushort_t* zfeat = (ushort_t*)carve((size_t)N_NODES * F_IN * 2);
    ushort_t* xa = (ushort_t*)carve((size_t)N_NODES * F_IN * 2);
    ushort_t* W1t = (ushort_t*)carve(256 * 128 * 2);
    ushort_t* W2t = (ushort_t*)carve(256 * 256 * 2);
    ushort_t* bufY = (ushort_t*)carve((size_t)N_NODES * 256 * 2);
    ushort_t* bufH = (ushort_t*)carve((size_t)N_NODES * 256 * 2);

    hipMemsetAsync(indeg, 0, N_NODES * 4 + 512 * 4, stream);  // indeg + gf

    histprep_kernel<<<2496, 256, 0, stream>>>(dst, W1, W2, fc1_w,
                                              indeg, W1t, W2t, fc1bf);
    scan_kernel<<<1, 256, 0, stream>>>(indeg, rowptr, cursor, dinv);
    fillz_kernel<<<4096, 256, 0, stream>>>(src, dst, cursor, col,
                                           features, dinv, zfeat);

    // layer 1 (aggregate-first): xa = dinv*Agg(z); h1 = relu(xa@W1 + b1)
    aggregate1<<<N_NODES / 4, 256, 0, stream>>>(zfeat, rowptr, col, dinv, xa);
    gemm_bf16<128, 128, true, false, true, true>
        <<<dim3(H1 / 128, N_NODES / 128), 256, 0, stream>>>(
            xa, W1t, (const float*)nullptr, b1, bufH, F_IN, H1);

    // layer 2: y = (h1@W2)*dinv
    gemm_bf16<128, 128, true, true, false, false>
        <<<dim3(H2 / 128, N_NODES / 128), 256, 0, stream>>>(
            bufH, W2t, dinv, (const float*)nullptr, bufY, H1, H2);

    // h2 = Agg'(y) + b2  (slim gather)
    aggregate2<<<N_NODES / 4, 256, 0, stream>>>(
        bufY, rowptr, col, dinv, b2, bufH);

    // assign = softmax(tanh(h2@fc1^T + fc1_b)@fc2^T + fc2_b)   (fused GEMM)
    gemm_assign<<<N_NODES / 128, 256, 0, stream>>>(
        bufH, fc1bf, fc1_b, fc2_w, fc2_b, assign);

    pool_kernel<<<256 + NEWADJ_BLOCKS, 256, 0, stream>>>(
        bufH, assign, src, dst, gf, napart);
    finalize_kernel<<<1, 256, 0, stream>>>(gf, napart, out);
}